// Round 8
// baseline (1303.022 us; speedup 1.0000x reference)
//
#include <hip/hip_runtime.h>

#define N_NODES 100000
#define M_PAD   100096   // multiple of 128 rows
#define N_EDGES 3200000
#define DIM 128
#define N_LAYERS 3
#define NUM_GRAPHS 128
#define BN_EPS 1e-5f

// ---- binned CSR build parameters ----
#define DST_SHIFT 7
#define BUCKET_NODES 128
#define N_BUCKETS ((N_NODES + BUCKET_NODES - 1) / BUCKET_NODES)  // 782
#define BUCKET_CAP 4864
#define EDGES_PER_BLOCK 16384
#define BIN_BLOCKS ((N_EDGES + EDGES_PER_BLOCK - 1) / EDGES_PER_BLOCK)  // 196

typedef unsigned int uint32;
typedef unsigned short u16;
typedef __attribute__((ext_vector_type(8))) short bf16x8;
typedef __attribute__((ext_vector_type(4))) float f32x4;

__device__ __forceinline__ float bf2f(u16 u) {
    union { uint32 i; float f; } c;
    c.i = ((uint32)u) << 16;
    return c.f;
}
__device__ __forceinline__ u16 f2bf(float f) {
    union { float f; uint32 i; } c;
    c.f = f;
    uint32 i = c.i;
    return (u16)((i + 0x7FFFu + ((i >> 16) & 1u)) >> 16);
}
__device__ __forceinline__ float lo_bf(uint32 v) {
    union { uint32 i; float f; } c;
    c.i = v << 16;
    return c.f;
}
__device__ __forceinline__ float hi_bf(uint32 v) {
    union { uint32 i; float f; } c;
    c.i = v & 0xFFFF0000u;
    return c.f;
}
__device__ __forceinline__ uint32 pack_bf2(float a, float b) {
    return ((uint32)f2bf(b) << 16) | (uint32)f2bf(a);
}

// h_cb layout: u16 element (cb, node, off) at ((cb*M_PAD + node)*16 + off)
// cb = col/16, off = col%16.

// ---------------------------------------------------------------------------
// zero_misc: one launch replaces all memsets
// ---------------------------------------------------------------------------
__global__ __launch_bounds__(256) void zero_misc(int* __restrict__ gcur,
                                                 float* __restrict__ bn_stats,
                                                 float* __restrict__ outp,
                                                 uint32* __restrict__ aggpad32,
                                                 int* __restrict__ dhist) {
    int i = blockIdx.x * 256 + threadIdx.x;
    if (i < N_BUCKETS) gcur[i] = 0;
    if (i < N_LAYERS * 2 * DIM) bn_stats[i] = 0.f;
    if (i < NUM_GRAPHS * DIM) outp[i] = 0.f;
    if (i < (M_PAD - N_NODES) * DIM / 2) aggpad32[i] = 0;
    if (i < 256) dhist[i] = 0;
}

// ---------------------------------------------------------------------------
// Stage A: bin edges by dst bucket (2-pass, coalesced). packed = src|(dst&127)<<17
// ---------------------------------------------------------------------------
__global__ __launch_bounds__(256) void bin_by_dst(const int* __restrict__ src,
                                                  const int* __restrict__ dst,
                                                  int* __restrict__ gcur,
                                                  uint32* __restrict__ packed) {
    __shared__ int cnt[N_BUCKETS];
    __shared__ int cur[N_BUCKETS];
    int t = threadIdx.x;
    int e0 = blockIdx.x * EDGES_PER_BLOCK;
    for (int i = t; i < N_BUCKETS; i += 256) cnt[i] = 0;
    __syncthreads();

    for (int j = 0; j < EDGES_PER_BLOCK / 256; ++j) {
        int e = e0 + j * 256 + t;
        if (e < N_EDGES) atomicAdd(&cnt[dst[e] >> DST_SHIFT], 1);
    }
    __syncthreads();
    for (int i = t; i < N_BUCKETS; i += 256) {
        int c = cnt[i];
        cur[i] = c ? atomicAdd(&gcur[i], c) : 0;
    }
    __syncthreads();
    for (int j = 0; j < EDGES_PER_BLOCK / 256; ++j) {
        int e = e0 + j * 256 + t;
        if (e < N_EDGES) {
            int d = dst[e];
            int b = d >> DST_SHIFT;
            int pos = atomicAdd(&cur[b], 1);
            if (pos < BUCKET_CAP)
                packed[(size_t)b * BUCKET_CAP + pos] =
                    (uint32)src[e] | ((uint32)(d & (BUCKET_NODES - 1)) << 17);
        }
    }
}

// ---------------------------------------------------------------------------
__global__ void scan_buckets(const int* __restrict__ gcur, int* __restrict__ obase,
                             int* __restrict__ row_ptr) {
    __shared__ int s[N_BUCKETS];
    int t = threadIdx.x;
    for (int i = t; i < N_BUCKETS; i += 256) {
        int c = gcur[i];
        s[i] = (c > BUCKET_CAP) ? BUCKET_CAP : c;
    }
    __syncthreads();
    if (t == 0) {
        int run = 0;
        for (int i = 0; i < N_BUCKETS; ++i) {
            int c = s[i];
            s[i] = run;
            run += c;
        }
        row_ptr[N_NODES] = run;
    }
    __syncthreads();
    for (int i = t; i < N_BUCKETS; i += 256) obase[i] = s[i];
}

// ---------------------------------------------------------------------------
// Stage B: per bucket — per-node row_ptr, place edges into col_src
// (band-sort removed: col-blocked aggregation is L2-resident regardless)
// ---------------------------------------------------------------------------
__global__ __launch_bounds__(256) void build_buckets(const uint32* __restrict__ packed,
                                                     const int* __restrict__ gcur,
                                                     const int* __restrict__ obase_arr,
                                                     int* __restrict__ row_ptr,
                                                     int* __restrict__ col_src) {
    __shared__ uint32 ed[BUCKET_CAP];
    __shared__ int ncnt[BUCKET_NODES];
    __shared__ int ncur[BUCKET_NODES];
    int b = blockIdx.x, t = threadIdx.x;
    int cnt = gcur[b];
    if (cnt > BUCKET_CAP) cnt = BUCKET_CAP;
    int obase = obase_arr[b];
    int n0 = b * BUCKET_NODES;

    if (t < BUCKET_NODES) ncnt[t] = 0;
    __syncthreads();

    const uint32* reg = packed + (size_t)b * BUCKET_CAP;
    for (int i = t; i < cnt; i += 256) {
        uint32 v = reg[i];
        ed[i] = v;
        atomicAdd(&ncnt[v >> 17], 1);
    }
    __syncthreads();

    int myc = (t < BUCKET_NODES) ? ncnt[t] : 0;
    if (t < BUCKET_NODES) ncur[t] = myc;
    __syncthreads();
    for (int off = 1; off < BUCKET_NODES; off <<= 1) {
        int v = 0;
        if (t < BUCKET_NODES && t >= off) v = ncur[t - off];
        __syncthreads();
        if (t < BUCKET_NODES) ncur[t] += v;
        __syncthreads();
    }
    if (t < BUCKET_NODES) {
        int excl = ncur[t] - myc;
        ncur[t] = excl;
        int gn = n0 + t;
        if (gn < N_NODES) row_ptr[gn] = obase + excl;
    }
    __syncthreads();

    for (int i = t; i < cnt; i += 256) {
        uint32 v = ed[i];
        int slot = atomicAdd(&ncur[v >> 17], 1);
        col_src[obase + slot] = (int)(v & 0x1FFFFu);
    }
}

// ---------------------------------------------------------------------------
// Degree-sort permutation: counting sort of nodes by degree (256 bins).
// Waves then process 8 same-degree nodes in lockstep -> no divergence tax.
// ---------------------------------------------------------------------------
__global__ __launch_bounds__(256) void deg_hist(const int* __restrict__ row_ptr,
                                                int* __restrict__ dhist) {
    int n = blockIdx.x * 256 + threadIdx.x;
    if (n < N_NODES) {
        int d = row_ptr[n + 1] - row_ptr[n];
        if (d > 255) d = 255;
        atomicAdd(&dhist[d], 1);
    }
}

__global__ void deg_scan(const int* __restrict__ dhist, int* __restrict__ dcur) {
    __shared__ int s[256];
    int t = threadIdx.x;
    int my = dhist[t];
    s[t] = my;
    __syncthreads();
    for (int off = 1; off < 256; off <<= 1) {
        int v = (t >= off) ? s[t - off] : 0;
        __syncthreads();
        s[t] += v;
        __syncthreads();
    }
    dcur[t] = s[t] - my;   // exclusive prefix
}

__global__ __launch_bounds__(256) void deg_scatter(const int* __restrict__ row_ptr,
                                                   int* __restrict__ dcur,
                                                   int* __restrict__ perm) {
    int n = blockIdx.x * 256 + threadIdx.x;
    if (n < N_NODES) {
        int d = row_ptr[n + 1] - row_ptr[n];
        if (d > 255) d = 255;
        int pos = atomicAdd(&dcur[d], 1);
        perm[pos] = n;
    }
}

// ---------------------------------------------------------------------------
// All 7 weight matrices -> WT bf16, transposed (n-major) AND pre-swizzled:
// element (n,k) at byte (n*256 + k*2) ^ ((n&7)<<4) within its matrix.
// ---------------------------------------------------------------------------
__global__ void cvt_wt_all(const float* __restrict__ Wn, const float* __restrict__ W1,
                           const float* __restrict__ W2, u16* __restrict__ WT) {
    int m = blockIdx.x >> 7, n = blockIdx.x & 127, k = threadIdx.x;
    const float* src = (m == 0) ? Wn
                     : (m <= 3) ? W1 + (size_t)(m - 1) * DIM * DIM
                                : W2 + (size_t)(m - 4) * DIM * DIM;
    int L = n * 256 + k * 2;
    int Ls = L ^ ((n & 7) << 4);
    *(u16*)((char*)WT + (size_t)m * 32768 + Ls) = f2bf(src[(size_t)k * DIM + n]);
}

// ---------------------------------------------------------------------------
// Aggregation v4 (column-blocked): block handles 32 nodes x ONE 16-col slice.
// blockIdx = chunk*8 + cb -> cb is constant per XCD (round-robin mapping), so
// each XCD's gather working set is h_cb[cb] = 3.2 MB, L2-resident.
// Group of 8 lanes owns one node: 2 cols/lane (uint32), unroll 4.
// ---------------------------------------------------------------------------
__global__ __launch_bounds__(256) void aggregate_cb(const u16* __restrict__ hcb,
                                                    const int* __restrict__ row_ptr,
                                                    const int* __restrict__ col_src,
                                                    const int* __restrict__ perm,
                                                    u16* __restrict__ agg) {
    int t = threadIdx.x;
    int cb = blockIdx.x & 7;
    int idx = (blockIdx.x >> 3) * 32 + (t >> 3);
    int l = t & 7;
    if (idx >= N_NODES) return;
    int n = perm[idx];
    const uint32* base = (const uint32*)hcb + (size_t)cb * M_PAD * 8;
    int beg = row_ptr[n], end = row_ptr[n + 1];

    uint32 sv = base[(size_t)n * 8 + l];      // self ((1+eps)*h, eps=0)
    float ax = lo_bf(sv), ay = hi_bf(sv);

    int e = beg;
    for (; e + 3 < end; e += 4) {
        int s0 = col_src[e], s1 = col_src[e + 1];
        int s2 = col_src[e + 2], s3 = col_src[e + 3];
        uint32 v0 = base[(size_t)s0 * 8 + l];
        uint32 v1 = base[(size_t)s1 * 8 + l];
        uint32 v2 = base[(size_t)s2 * 8 + l];
        uint32 v3 = base[(size_t)s3 * 8 + l];
        ax += lo_bf(v0); ay += hi_bf(v0);
        ax += lo_bf(v1); ay += hi_bf(v1);
        ax += lo_bf(v2); ay += hi_bf(v2);
        ax += lo_bf(v3); ay += hi_bf(v3);
    }
    for (; e < end; ++e) {
        uint32 v = base[(size_t)col_src[e] * 8 + l];
        ax += lo_bf(v); ay += hi_bf(v);
    }
    // agg stays row-major: row n, cols [cb*16 + 2l, +1]
    ((uint32*)agg)[(size_t)n * 64 + cb * 8 + l] = pack_bf2(ax, ay);
}

// ---------------------------------------------------------------------------
// GEMM v2.2: 128 rows x 128 cols per block (256 thr = 4 waves).
// B (32 KB, pre-swizzled) in LDS; A loads hoisted before the stage barrier.
// MODE 0: A = f32 x (fused cvt)              -> h_cb = A@W + b     (colb out)
// MODE 1: A = bf16 agg (row), stats epilogue -> y = A@W1 + b1      (row out)
// MODE 2: A = bf16 y (row), BN+ReLU pre/post -> h_cb = ...         (colb out)
// ---------------------------------------------------------------------------
template <int MODE>
__global__ __launch_bounds__(256) void gemm_v2(const void* __restrict__ Av,
                                               const u16* __restrict__ WTs,
                                               const float* __restrict__ bias,
                                               u16* __restrict__ outp,
                                               float* __restrict__ bn_sum,
                                               float* __restrict__ bn_sumsq,
                                               const float* __restrict__ gamma,
                                               const float* __restrict__ beta) {
    __shared__ u16 sB[DIM * DIM];     // 32 KB swizzled
    __shared__ float sc_[DIM];
    __shared__ float sh_[DIM];
    __shared__ float ls[4][DIM];
    __shared__ float lq[4][DIM];

    int t = threadIdx.x;
    int wid = t >> 6, lane = t & 63;
    int hw = lane >> 4, c = lane & 15;
    int row0 = blockIdx.x * 128 + wid * 32;

    // ---- issue A loads FIRST ----
    bf16x8 a[2][4];
    float4 af[2][4][2];
#pragma unroll
    for (int rf = 0; rf < 2; ++rf) {
        int row = row0 + rf * 16 + c;
#pragma unroll
        for (int ks = 0; ks < 4; ++ks) {
            int k0 = ks * 32 + hw * 8;
            if (MODE == 0) {
                const float* xf = (const float*)Av;
                af[rf][ks][0] = make_float4(0.f, 0.f, 0.f, 0.f);
                af[rf][ks][1] = af[rf][ks][0];
                if (row < N_NODES) {
                    af[rf][ks][0] = *(const float4*)&xf[(size_t)row * DIM + k0];
                    af[rf][ks][1] = *(const float4*)&xf[(size_t)row * DIM + k0 + 4];
                }
            } else {
                const u16* Ab = (const u16*)Av;
                a[rf][ks] = *(const bf16x8*)&Ab[(size_t)row * DIM + k0];
            }
        }
    }

    // ---- stage B (linear copy; swizzle baked into global layout) ----
    {
        const uint4* Wg = (const uint4*)WTs;
        uint4* sB4 = (uint4*)sB;
#pragma unroll
        for (int i = 0; i < 8; ++i) sB4[i * 256 + t] = Wg[i * 256 + t];
    }
    if (MODE == 2 && t < DIM) {
        const float invN = 1.0f / (float)N_NODES;
        float mean = bn_sum[t] * invN;
        float var = fmaxf(bn_sumsq[t] * invN - mean * mean, 0.f);
        float rs = rsqrtf(var + BN_EPS);
        float sc = gamma[t] * rs;
        sc_[t] = sc;
        sh_[t] = beta[t] - mean * sc;
    }
    __syncthreads();

    // ---- finish A fragments in registers ----
#pragma unroll
    for (int rf = 0; rf < 2; ++rf) {
#pragma unroll
        for (int ks = 0; ks < 4; ++ks) {
            int k0 = ks * 32 + hw * 8;
            if (MODE == 0) {
                union { bf16x8 v; u16 u[8]; } ua;
                float4 v0 = af[rf][ks][0], v1 = af[rf][ks][1];
                ua.u[0] = f2bf(v0.x); ua.u[1] = f2bf(v0.y);
                ua.u[2] = f2bf(v0.z); ua.u[3] = f2bf(v0.w);
                ua.u[4] = f2bf(v1.x); ua.u[5] = f2bf(v1.y);
                ua.u[6] = f2bf(v1.z); ua.u[7] = f2bf(v1.w);
                a[rf][ks] = ua.v;
            } else if (MODE == 2) {
                union { bf16x8 v; u16 u[8]; } ua;
                ua.v = a[rf][ks];
#pragma unroll
                for (int j = 0; j < 8; ++j) {
                    float f = bf2f(ua.u[j]);
                    f = fmaxf(fmaf(f, sc_[k0 + j], sh_[k0 + j]), 0.f);
                    ua.u[j] = f2bf(f);
                }
                a[rf][ks] = ua.v;
            }
        }
    }

    // ---- MFMA from LDS B ----
    f32x4 acc[2][8];
#pragma unroll
    for (int rf = 0; rf < 2; ++rf)
#pragma unroll
        for (int nf = 0; nf < 8; ++nf) acc[rf][nf] = (f32x4){0.f, 0.f, 0.f, 0.f};

    int swz = (c & 7) << 4;
#pragma unroll
    for (int ks = 0; ks < 4; ++ks) {
#pragma unroll
        for (int nf = 0; nf < 8; ++nf) {
            int L = (nf * 4096 + c * 256 + ks * 64 + hw * 16) ^ swz;
            bf16x8 b = *(const bf16x8*)((const char*)sB + L);
            acc[0][nf] = __builtin_amdgcn_mfma_f32_16x16x32_bf16(a[0][ks], b, acc[0][nf], 0, 0, 0);
            acc[1][nf] = __builtin_amdgcn_mfma_f32_16x16x32_bf16(a[1][ks], b, acc[1][nf], 0, 0, 0);
        }
    }

    // ---- epilogue ----
    float s_[8], q_[8];
#pragma unroll
    for (int nf = 0; nf < 8; ++nf) { s_[nf] = 0.f; q_[nf] = 0.f; }

#pragma unroll
    for (int rf = 0; rf < 2; ++rf) {
        int rbase = row0 + rf * 16 + hw * 4;
#pragma unroll
        for (int nf = 0; nf < 8; ++nf) {
            float bv = bias[nf * 16 + c];
#pragma unroll
            for (int r = 0; r < 4; ++r) {
                float v = acc[rf][nf][r] + bv;
                if (MODE == 2) v = fmaxf(v, 0.f);
                u16 o = f2bf(v);
                if (MODE == 1) {
                    outp[(size_t)(rbase + r) * DIM + nf * 16 + c] = o;   // row-major
                    float m = (rbase + r < N_NODES) ? v : 0.f;
                    s_[nf] += m;
                    q_[nf] += m * m;
                } else {
                    // col-blocked: cb = nf, off = c
                    outp[((size_t)nf * M_PAD + (rbase + r)) * 16 + c] = o;
                }
            }
        }
    }

    if (MODE == 1) {
#pragma unroll
        for (int nf = 0; nf < 8; ++nf) {
            s_[nf] += __shfl_xor(s_[nf], 16);
            s_[nf] += __shfl_xor(s_[nf], 32);
            q_[nf] += __shfl_xor(q_[nf], 16);
            q_[nf] += __shfl_xor(q_[nf], 32);
        }
        if (lane < 16) {
#pragma unroll
            for (int nf = 0; nf < 8; ++nf) {
                ls[wid][nf * 16 + c] = s_[nf];
                lq[wid][nf * 16 + c] = q_[nf];
            }
        }
        __syncthreads();
        if (t < DIM) {
            atomicAdd(&bn_sum[t], ls[0][t] + ls[1][t] + ls[2][t] + ls[3][t]);
            atomicAdd(&bn_sumsq[t], lq[0][t] + lq[1][t] + lq[2][t] + lq[3][t]);
        }
    }
}

// ---------------------------------------------------------------------------
// Global add pool (col-blocked h, f32 out); batch sorted, wave per 32 nodes.
// lane: cb = lane>>3, l = lane&7 -> cols [cb*16+2l, +1]
// ---------------------------------------------------------------------------
__global__ __launch_bounds__(256) void pool_cb(const u16* __restrict__ hcb,
                                               const int* __restrict__ batch,
                                               float* __restrict__ out) {
    int wv = (blockIdx.x * 256 + threadIdx.x) >> 6;
    int lane = threadIdx.x & 63;
    int cb = lane >> 3, l = lane & 7;
    int base = wv * 32;
    if (base >= N_NODES) return;
    int end = base + 32;
    if (end > N_NODES) end = N_NODES;
    const uint32* b32 = (const uint32*)hcb + (size_t)cb * M_PAD * 8;
    int col = cb * 16 + l * 2;
    float ax = 0.f, ay = 0.f;
    int curg = batch[base];
    for (int n = base; n < end; ++n) {
        int g = batch[n];
        if (g != curg) {
            atomicAdd(&out[curg * DIM + col], ax);
            atomicAdd(&out[curg * DIM + col + 1], ay);
            ax = 0.f;
            ay = 0.f;
            curg = g;
        }
        uint32 v = b32[(size_t)n * 8 + l];
        ax += lo_bf(v);
        ay += hi_bf(v);
    }
    atomicAdd(&out[curg * DIM + col], ax);
    atomicAdd(&out[curg * DIM + col + 1], ay);
}

// ---------------------------------------------------------------------------
extern "C" void kernel_launch(void* const* d_in, const int* in_sizes, int n_in,
                              void* d_out, int out_size, void* d_ws, size_t ws_size,
                              hipStream_t stream) {
    const float* x     = (const float*)d_in[0];
    const int*   ei    = (const int*)d_in[1];
    const int*   batch = (const int*)d_in[2];
    const float* Wn    = (const float*)d_in[3];
    const float* bnode = (const float*)d_in[4];
    const float* W1    = (const float*)d_in[5];
    const float* b1    = (const float*)d_in[6];
    const float* gamma = (const float*)d_in[7];
    const float* beta  = (const float*)d_in[8];
    const float* W2    = (const float*)d_in[9];
    const float* b2    = (const float*)d_in[10];
    float* out = (float*)d_out;

    const int* e_src = ei;
    const int* e_dst = ei + N_EDGES;

    // workspace layout
    const size_t MD = (size_t)M_PAD * DIM;
    u16* h   = (u16*)d_ws;                  // col-blocked: [8][M_PAD][16]
    u16* agg = h + MD;                      // row-major
    u16* y   = agg + MD;                    // row-major
    u16* WT  = y + MD;                      // 7 * 128 * 128 bf16, pre-swizzled
    int* row_ptr = (int*)(WT + 7 * DIM * DIM);
    int* col_src = row_ptr + N_NODES + 1;
    int* gcur    = col_src + N_EDGES;
    int* obase   = gcur + N_BUCKETS;
    int* dhist   = obase + N_BUCKETS;       // 256
    int* dcur    = dhist + 256;             // 256
    int* perm    = dcur + 256;              // N_NODES
    float* bn_stats = (float*)(perm + N_NODES);   // 3 layers * 2 * DIM
    // packed aliases y: used only during CSR build, before any GEMM writes y
    uint32* packed = (uint32*)y;            // 782*4864*4 B = 15.2 MB <= 25.6 MB

    const int GEMM_BLOCKS = M_PAD / 128;                     // 782
    const int AGG_BLOCKS = ((N_NODES + 31) / 32) * 8;        // 25000
    const int POOL_BLOCKS = (((N_NODES + 31) / 32) * 64 + 255) / 256;
    const int NODE_BLOCKS = (N_NODES + 255) / 256;           // 391

    // ---- init + CSR build ----
    zero_misc<<<64, 256, 0, stream>>>(gcur, bn_stats, out,
                                      (uint32*)(agg + (size_t)N_NODES * DIM), dhist);
    bin_by_dst<<<BIN_BLOCKS, 256, 0, stream>>>(e_src, e_dst, gcur, packed);
    scan_buckets<<<1, 256, 0, stream>>>(gcur, obase, row_ptr);
    build_buckets<<<N_BUCKETS, 256, 0, stream>>>(packed, gcur, obase, row_ptr, col_src);

    // ---- degree-sort permutation ----
    deg_hist<<<NODE_BLOCKS, 256, 0, stream>>>(row_ptr, dhist);
    deg_scan<<<1, 256, 0, stream>>>(dhist, dcur);
    deg_scatter<<<NODE_BLOCKS, 256, 0, stream>>>(row_ptr, dcur, perm);

    // ---- weights (transposed + swizzled bf16) ----
    cvt_wt_all<<<7 * DIM, DIM, 0, stream>>>(Wn, W1, W2, WT);

    // ---- node encoder (fused f32->bf16, col-blocked h out) ----
    gemm_v2<0><<<GEMM_BLOCKS, 256, 0, stream>>>(x, WT, bnode, h, nullptr,
                                                nullptr, nullptr, nullptr);

    // ---- GIN layers ----
    for (int i = 0; i < N_LAYERS; ++i) {
        float* bn_sum = bn_stats + (size_t)i * 2 * DIM;
        float* bn_sumsq = bn_sum + DIM;
        aggregate_cb<<<AGG_BLOCKS, 256, 0, stream>>>(h, row_ptr, col_src, perm, agg);
        gemm_v2<1><<<GEMM_BLOCKS, 256, 0, stream>>>(
            agg, WT + (size_t)(1 + i) * DIM * DIM, b1 + i * DIM, y, bn_sum,
            bn_sumsq, nullptr, nullptr);
        gemm_v2<2><<<GEMM_BLOCKS, 256, 0, stream>>>(
            y, WT + (size_t)(4 + i) * DIM * DIM, b2 + i * DIM, h, bn_sum,
            bn_sumsq, gamma + i * DIM, beta + i * DIM);
    }

    // ---- global add pool ----
    pool_cb<<<POOL_BLOCKS, 256, 0, stream>>>(h, batch, out);
}

// Round 9
// 1015.572 us; speedup vs baseline: 1.2830x; 1.2830x over previous
//
#include <hip/hip_runtime.h>

#define N_NODES 100000
#define M_PAD   100096   // multiple of 128 rows
#define N_EDGES 3200000
#define DIM 128
#define N_LAYERS 3
#define NUM_GRAPHS 128
#define BN_EPS 1e-5f

// ---- binned CSR build parameters ----
#define DST_SHIFT 7
#define BUCKET_NODES 128
#define N_BUCKETS ((N_NODES + BUCKET_NODES - 1) / BUCKET_NODES)  // 782
#define BUCKET_CAP 4864
#define EDGES_PER_BLOCK 16384
#define BIN_BLOCKS ((N_EDGES + EDGES_PER_BLOCK - 1) / EDGES_PER_BLOCK)  // 196

typedef unsigned int uint32;
typedef unsigned short u16;
typedef __attribute__((ext_vector_type(8))) short bf16x8;
typedef __attribute__((ext_vector_type(4))) float f32x4;

__device__ __forceinline__ float bf2f(u16 u) {
    union { uint32 i; float f; } c;
    c.i = ((uint32)u) << 16;
    return c.f;
}
__device__ __forceinline__ u16 f2bf(float f) {
    union { float f; uint32 i; } c;
    c.f = f;
    uint32 i = c.i;
    return (u16)((i + 0x7FFFu + ((i >> 16) & 1u)) >> 16);
}
__device__ __forceinline__ float lo_bf(uint32 v) {
    union { uint32 i; float f; } c;
    c.i = v << 16;
    return c.f;
}
__device__ __forceinline__ float hi_bf(uint32 v) {
    union { uint32 i; float f; } c;
    c.i = v & 0xFFFF0000u;
    return c.f;
}
__device__ __forceinline__ uint32 pack_bf2(float a, float b) {
    return ((uint32)f2bf(b) << 16) | (uint32)f2bf(a);
}

// h_cb layout: u16 element (cb, node, off) at ((cb*M_PAD + node)*16 + off)

// ---------------------------------------------------------------------------
// zero_misc: one launch replaces all memsets
// ---------------------------------------------------------------------------
__global__ __launch_bounds__(256) void zero_misc(int* __restrict__ gcur,
                                                 float* __restrict__ bn_stats,
                                                 float* __restrict__ outp,
                                                 uint32* __restrict__ aggpad32) {
    int i = blockIdx.x * 256 + threadIdx.x;
    if (i < N_BUCKETS) gcur[i] = 0;
    if (i < N_LAYERS * 2 * DIM) bn_stats[i] = 0.f;
    if (i < NUM_GRAPHS * DIM) outp[i] = 0.f;
    if (i < (M_PAD - N_NODES) * DIM / 2) aggpad32[i] = 0;
}

// ---------------------------------------------------------------------------
// Stage A: bin edges by dst bucket (2-pass, coalesced). packed = src|(dst&127)<<17
// ---------------------------------------------------------------------------
__global__ __launch_bounds__(256) void bin_by_dst(const int* __restrict__ src,
                                                  const int* __restrict__ dst,
                                                  int* __restrict__ gcur,
                                                  uint32* __restrict__ packed) {
    __shared__ int cnt[N_BUCKETS];
    __shared__ int cur[N_BUCKETS];
    int t = threadIdx.x;
    int e0 = blockIdx.x * EDGES_PER_BLOCK;
    for (int i = t; i < N_BUCKETS; i += 256) cnt[i] = 0;
    __syncthreads();

    for (int j = 0; j < EDGES_PER_BLOCK / 256; ++j) {
        int e = e0 + j * 256 + t;
        if (e < N_EDGES) atomicAdd(&cnt[dst[e] >> DST_SHIFT], 1);
    }
    __syncthreads();
    for (int i = t; i < N_BUCKETS; i += 256) {
        int c = cnt[i];
        cur[i] = c ? atomicAdd(&gcur[i], c) : 0;
    }
    __syncthreads();
    for (int j = 0; j < EDGES_PER_BLOCK / 256; ++j) {
        int e = e0 + j * 256 + t;
        if (e < N_EDGES) {
            int d = dst[e];
            int b = d >> DST_SHIFT;
            int pos = atomicAdd(&cur[b], 1);
            if (pos < BUCKET_CAP)
                packed[(size_t)b * BUCKET_CAP + pos] =
                    (uint32)src[e] | ((uint32)(d & (BUCKET_NODES - 1)) << 17);
        }
    }
}

// ---------------------------------------------------------------------------
__global__ void scan_buckets(const int* __restrict__ gcur, int* __restrict__ obase,
                             int* __restrict__ row_ptr) {
    __shared__ int s[N_BUCKETS];
    int t = threadIdx.x;
    for (int i = t; i < N_BUCKETS; i += 256) {
        int c = gcur[i];
        s[i] = (c > BUCKET_CAP) ? BUCKET_CAP : c;
    }
    __syncthreads();
    if (t == 0) {
        int run = 0;
        for (int i = 0; i < N_BUCKETS; ++i) {
            int c = s[i];
            s[i] = run;
            run += c;
        }
        row_ptr[N_NODES] = run;
    }
    __syncthreads();
    for (int i = t; i < N_BUCKETS; i += 256) obase[i] = s[i];
}

// ---------------------------------------------------------------------------
// Stage B: per bucket — per-node row_ptr, place edges into col_src
// ---------------------------------------------------------------------------
__global__ __launch_bounds__(256) void build_buckets(const uint32* __restrict__ packed,
                                                     const int* __restrict__ gcur,
                                                     const int* __restrict__ obase_arr,
                                                     int* __restrict__ row_ptr,
                                                     int* __restrict__ col_src) {
    __shared__ uint32 ed[BUCKET_CAP];
    __shared__ int ncnt[BUCKET_NODES];
    __shared__ int ncur[BUCKET_NODES];
    int b = blockIdx.x, t = threadIdx.x;
    int cnt = gcur[b];
    if (cnt > BUCKET_CAP) cnt = BUCKET_CAP;
    int obase = obase_arr[b];
    int n0 = b * BUCKET_NODES;

    if (t < BUCKET_NODES) ncnt[t] = 0;
    __syncthreads();

    const uint32* reg = packed + (size_t)b * BUCKET_CAP;
    for (int i = t; i < cnt; i += 256) {
        uint32 v = reg[i];
        ed[i] = v;
        atomicAdd(&ncnt[v >> 17], 1);
    }
    __syncthreads();

    int myc = (t < BUCKET_NODES) ? ncnt[t] : 0;
    if (t < BUCKET_NODES) ncur[t] = myc;
    __syncthreads();
    for (int off = 1; off < BUCKET_NODES; off <<= 1) {
        int v = 0;
        if (t < BUCKET_NODES && t >= off) v = ncur[t - off];
        __syncthreads();
        if (t < BUCKET_NODES) ncur[t] += v;
        __syncthreads();
    }
    if (t < BUCKET_NODES) {
        int excl = ncur[t] - myc;
        ncur[t] = excl;
        int gn = n0 + t;
        if (gn < N_NODES) row_ptr[gn] = obase + excl;
    }
    __syncthreads();

    for (int i = t; i < cnt; i += 256) {
        uint32 v = ed[i];
        int slot = atomicAdd(&ncur[v >> 17], 1);
        col_src[obase + slot] = (int)(v & 0x1FFFFu);
    }
}

// ---------------------------------------------------------------------------
// All 7 weight matrices -> WT bf16, transposed (n-major) AND pre-swizzled:
// element (n,k) at byte (n*256 + k*2) ^ ((n&7)<<4) within its matrix.
// ---------------------------------------------------------------------------
__global__ void cvt_wt_all(const float* __restrict__ Wn, const float* __restrict__ W1,
                           const float* __restrict__ W2, u16* __restrict__ WT) {
    int m = blockIdx.x >> 7, n = blockIdx.x & 127, k = threadIdx.x;
    const float* src = (m == 0) ? Wn
                     : (m <= 3) ? W1 + (size_t)(m - 1) * DIM * DIM
                                : W2 + (size_t)(m - 4) * DIM * DIM;
    int L = n * 256 + k * 2;
    int Ls = L ^ ((n & 7) << 4);
    *(u16*)((char*)WT + (size_t)m * 32768 + Ls) = f2bf(src[(size_t)k * DIM + n]);
}

// ---------------------------------------------------------------------------
// Aggregation v5 (column-blocked, wave-per-node): one wave handles one node's
// full edge list for ONE 16-col slice. 8 groups x 8 lanes: group g loads edge
// beg+g, beg+g+8, ...; lane l holds cols [2l, 2l+1] (4 B). Cross-group
// shfl_xor reduce at the end. Loop length uniform across the wave -> no
// divergence. blockIdx = chunk*8 + cb keeps cb constant per XCD (3.2 MB
// slice, L2-resident).
// ---------------------------------------------------------------------------
__global__ __launch_bounds__(256) void aggregate_cb(const u16* __restrict__ hcb,
                                                    const int* __restrict__ row_ptr,
                                                    const int* __restrict__ col_src,
                                                    u16* __restrict__ agg) {
    int t = threadIdx.x;
    int cb = blockIdx.x & 7;
    int n = (blockIdx.x >> 3) * 4 + (t >> 6);
    if (n >= N_NODES) return;
    int lane = t & 63;
    int g = lane >> 3, l = lane & 7;
    const uint32* base = (const uint32*)hcb + (size_t)cb * M_PAD * 8;
    int beg = row_ptr[n], end = row_ptr[n + 1];

    float ax = 0.f, ay = 0.f;
    if (g == 0) {  // self ((1+eps)*h, eps=0)
        uint32 sv = base[(size_t)n * 8 + l];
        ax = lo_bf(sv);
        ay = hi_bf(sv);
    }
    int e = beg + g;
    for (; e + 8 < end; e += 16) {
        int s0 = col_src[e];
        int s1 = col_src[e + 8];
        uint32 v0 = base[(size_t)s0 * 8 + l];
        uint32 v1 = base[(size_t)s1 * 8 + l];
        ax += lo_bf(v0); ay += hi_bf(v0);
        ax += lo_bf(v1); ay += hi_bf(v1);
    }
    if (e < end) {
        uint32 v = base[(size_t)col_src[e] * 8 + l];
        ax += lo_bf(v); ay += hi_bf(v);
    }
    // reduce across the 8 groups
    ax += __shfl_xor(ax, 8);  ay += __shfl_xor(ay, 8);
    ax += __shfl_xor(ax, 16); ay += __shfl_xor(ay, 16);
    ax += __shfl_xor(ax, 32); ay += __shfl_xor(ay, 32);
    if (g == 0)
        ((uint32*)agg)[(size_t)n * 64 + cb * 8 + l] = pack_bf2(ax, ay);
}

// ---------------------------------------------------------------------------
// GEMM v2.2: 128 rows x 128 cols per block (256 thr = 4 waves).
// B (32 KB, pre-swizzled) in LDS; A loads hoisted before the stage barrier.
// MODE 0: A = f32 x (fused cvt)              -> h_cb = A@W + b     (colb out)
// MODE 1: A = bf16 agg (row), stats epilogue -> y = A@W1 + b1      (row out)
// MODE 2: A = bf16 y (row), BN+ReLU pre/post -> h_cb = ...         (colb out)
// ---------------------------------------------------------------------------
template <int MODE>
__global__ __launch_bounds__(256) void gemm_v2(const void* __restrict__ Av,
                                               const u16* __restrict__ WTs,
                                               const float* __restrict__ bias,
                                               u16* __restrict__ outp,
                                               float* __restrict__ bn_sum,
                                               float* __restrict__ bn_sumsq,
                                               const float* __restrict__ gamma,
                                               const float* __restrict__ beta) {
    __shared__ u16 sB[DIM * DIM];     // 32 KB swizzled
    __shared__ float sc_[DIM];
    __shared__ float sh_[DIM];
    __shared__ float ls[4][DIM];
    __shared__ float lq[4][DIM];

    int t = threadIdx.x;
    int wid = t >> 6, lane = t & 63;
    int hw = lane >> 4, c = lane & 15;
    int row0 = blockIdx.x * 128 + wid * 32;

    // ---- issue A loads FIRST ----
    bf16x8 a[2][4];
    float4 af[2][4][2];
#pragma unroll
    for (int rf = 0; rf < 2; ++rf) {
        int row = row0 + rf * 16 + c;
#pragma unroll
        for (int ks = 0; ks < 4; ++ks) {
            int k0 = ks * 32 + hw * 8;
            if (MODE == 0) {
                const float* xf = (const float*)Av;
                af[rf][ks][0] = make_float4(0.f, 0.f, 0.f, 0.f);
                af[rf][ks][1] = af[rf][ks][0];
                if (row < N_NODES) {
                    af[rf][ks][0] = *(const float4*)&xf[(size_t)row * DIM + k0];
                    af[rf][ks][1] = *(const float4*)&xf[(size_t)row * DIM + k0 + 4];
                }
            } else {
                const u16* Ab = (const u16*)Av;
                a[rf][ks] = *(const bf16x8*)&Ab[(size_t)row * DIM + k0];
            }
        }
    }

    // ---- stage B (linear copy; swizzle baked into global layout) ----
    {
        const uint4* Wg = (const uint4*)WTs;
        uint4* sB4 = (uint4*)sB;
#pragma unroll
        for (int i = 0; i < 8; ++i) sB4[i * 256 + t] = Wg[i * 256 + t];
    }
    if (MODE == 2 && t < DIM) {
        const float invN = 1.0f / (float)N_NODES;
        float mean = bn_sum[t] * invN;
        float var = fmaxf(bn_sumsq[t] * invN - mean * mean, 0.f);
        float rs = rsqrtf(var + BN_EPS);
        float sc = gamma[t] * rs;
        sc_[t] = sc;
        sh_[t] = beta[t] - mean * sc;
    }
    __syncthreads();

    // ---- finish A fragments in registers ----
#pragma unroll
    for (int rf = 0; rf < 2; ++rf) {
#pragma unroll
        for (int ks = 0; ks < 4; ++ks) {
            int k0 = ks * 32 + hw * 8;
            if (MODE == 0) {
                union { bf16x8 v; u16 u[8]; } ua;
                float4 v0 = af[rf][ks][0], v1 = af[rf][ks][1];
                ua.u[0] = f2bf(v0.x); ua.u[1] = f2bf(v0.y);
                ua.u[2] = f2bf(v0.z); ua.u[3] = f2bf(v0.w);
                ua.u[4] = f2bf(v1.x); ua.u[5] = f2bf(v1.y);
                ua.u[6] = f2bf(v1.z); ua.u[7] = f2bf(v1.w);
                a[rf][ks] = ua.v;
            } else if (MODE == 2) {
                union { bf16x8 v; u16 u[8]; } ua;
                ua.v = a[rf][ks];
#pragma unroll
                for (int j = 0; j < 8; ++j) {
                    float f = bf2f(ua.u[j]);
                    f = fmaxf(fmaf(f, sc_[k0 + j], sh_[k0 + j]), 0.f);
                    ua.u[j] = f2bf(f);
                }
                a[rf][ks] = ua.v;
            }
        }
    }

    // ---- MFMA from LDS B ----
    f32x4 acc[2][8];
#pragma unroll
    for (int rf = 0; rf < 2; ++rf)
#pragma unroll
        for (int nf = 0; nf < 8; ++nf) acc[rf][nf] = (f32x4){0.f, 0.f, 0.f, 0.f};

    int swz = (c & 7) << 4;
#pragma unroll
    for (int ks = 0; ks < 4; ++ks) {
#pragma unroll
        for (int nf = 0; nf < 8; ++nf) {
            int L = (nf * 4096 + c * 256 + ks * 64 + hw * 16) ^ swz;
            bf16x8 b = *(const bf16x8*)((const char*)sB + L);
            acc[0][nf] = __builtin_amdgcn_mfma_f32_16x16x32_bf16(a[0][ks], b, acc[0][nf], 0, 0, 0);
            acc[1][nf] = __builtin_amdgcn_mfma_f32_16x16x32_bf16(a[1][ks], b, acc[1][nf], 0, 0, 0);
        }
    }

    // ---- epilogue ----
    float s_[8], q_[8];
#pragma unroll
    for (int nf = 0; nf < 8; ++nf) { s_[nf] = 0.f; q_[nf] = 0.f; }

#pragma unroll
    for (int rf = 0; rf < 2; ++rf) {
        int rbase = row0 + rf * 16 + hw * 4;
#pragma unroll
        for (int nf = 0; nf < 8; ++nf) {
            float bv = bias[nf * 16 + c];
#pragma unroll
            for (int r = 0; r < 4; ++r) {
                float v = acc[rf][nf][r] + bv;
                if (MODE == 2) v = fmaxf(v, 0.f);
                u16 o = f2bf(v);
                if (MODE == 1) {
                    outp[(size_t)(rbase + r) * DIM + nf * 16 + c] = o;   // row-major
                    float m = (rbase + r < N_NODES) ? v : 0.f;
                    s_[nf] += m;
                    q_[nf] += m * m;
                } else {
                    // col-blocked: cb = nf, off = c
                    outp[((size_t)nf * M_PAD + (rbase + r)) * 16 + c] = o;
                }
            }
        }
    }

    if (MODE == 1) {
#pragma unroll
        for (int nf = 0; nf < 8; ++nf) {
            s_[nf] += __shfl_xor(s_[nf], 16);
            s_[nf] += __shfl_xor(s_[nf], 32);
            q_[nf] += __shfl_xor(q_[nf], 16);
            q_[nf] += __shfl_xor(q_[nf], 32);
        }
        if (lane < 16) {
#pragma unroll
            for (int nf = 0; nf < 8; ++nf) {
                ls[wid][nf * 16 + c] = s_[nf];
                lq[wid][nf * 16 + c] = q_[nf];
            }
        }
        __syncthreads();
        if (t < DIM) {
            atomicAdd(&bn_sum[t], ls[0][t] + ls[1][t] + ls[2][t] + ls[3][t]);
            atomicAdd(&bn_sumsq[t], lq[0][t] + lq[1][t] + lq[2][t] + lq[3][t]);
        }
    }
}

// ---------------------------------------------------------------------------
// Global add pool (col-blocked h, f32 out); batch sorted, wave per 32 nodes.
// ---------------------------------------------------------------------------
__global__ __launch_bounds__(256) void pool_cb(const u16* __restrict__ hcb,
                                               const int* __restrict__ batch,
                                               float* __restrict__ out) {
    int wv = (blockIdx.x * 256 + threadIdx.x) >> 6;
    int lane = threadIdx.x & 63;
    int cb = lane >> 3, l = lane & 7;
    int base = wv * 32;
    if (base >= N_NODES) return;
    int end = base + 32;
    if (end > N_NODES) end = N_NODES;
    const uint32* b32 = (const uint32*)hcb + (size_t)cb * M_PAD * 8;
    int col = cb * 16 + l * 2;
    float ax = 0.f, ay = 0.f;
    int curg = batch[base];
    for (int n = base; n < end; ++n) {
        int g = batch[n];
        if (g != curg) {
            atomicAdd(&out[curg * DIM + col], ax);
            atomicAdd(&out[curg * DIM + col + 1], ay);
            ax = 0.f;
            ay = 0.f;
            curg = g;
        }
        uint32 v = b32[(size_t)n * 8 + l];
        ax += lo_bf(v);
        ay += hi_bf(v);
    }
    atomicAdd(&out[curg * DIM + col], ax);
    atomicAdd(&out[curg * DIM + col + 1], ay);
}

// ---------------------------------------------------------------------------
extern "C" void kernel_launch(void* const* d_in, const int* in_sizes, int n_in,
                              void* d_out, int out_size, void* d_ws, size_t ws_size,
                              hipStream_t stream) {
    const float* x     = (const float*)d_in[0];
    const int*   ei    = (const int*)d_in[1];
    const int*   batch = (const int*)d_in[2];
    const float* Wn    = (const float*)d_in[3];
    const float* bnode = (const float*)d_in[4];
    const float* W1    = (const float*)d_in[5];
    const float* b1    = (const float*)d_in[6];
    const float* gamma = (const float*)d_in[7];
    const float* beta  = (const float*)d_in[8];
    const float* W2    = (const float*)d_in[9];
    const float* b2    = (const float*)d_in[10];
    float* out = (float*)d_out;

    const int* e_src = ei;
    const int* e_dst = ei + N_EDGES;

    // workspace layout
    const size_t MD = (size_t)M_PAD * DIM;
    u16* h   = (u16*)d_ws;                  // col-blocked: [8][M_PAD][16]
    u16* agg = h + MD;                      // row-major
    u16* y   = agg + MD;                    // row-major
    u16* WT  = y + MD;                      // 7 * 128 * 128 bf16, pre-swizzled
    int* row_ptr = (int*)(WT + 7 * DIM * DIM);
    int* col_src = row_ptr + N_NODES + 1;
    int* gcur    = col_src + N_EDGES;
    int* obase   = gcur + N_BUCKETS;
    float* bn_stats = (float*)(obase + N_BUCKETS);   // 3 layers * 2 * DIM
    // packed aliases y: used only during CSR build, before any GEMM writes y
    uint32* packed = (uint32*)y;            // 782*4864*4 B = 15.2 MB <= 25.6 MB

    const int GEMM_BLOCKS = M_PAD / 128;                     // 782
    const int AGG_BLOCKS = ((N_NODES + 3) / 4) * 8;          // 200000
    const int POOL_BLOCKS = (((N_NODES + 31) / 32) * 64 + 255) / 256;

    // ---- init + CSR build ----
    zero_misc<<<64, 256, 0, stream>>>(gcur, bn_stats, out,
                                      (uint32*)(agg + (size_t)N_NODES * DIM));
    bin_by_dst<<<BIN_BLOCKS, 256, 0, stream>>>(e_src, e_dst, gcur, packed);
    scan_buckets<<<1, 256, 0, stream>>>(gcur, obase, row_ptr);
    build_buckets<<<N_BUCKETS, 256, 0, stream>>>(packed, gcur, obase, row_ptr, col_src);

    // ---- weights (transposed + swizzled bf16) ----
    cvt_wt_all<<<7 * DIM, DIM, 0, stream>>>(Wn, W1, W2, WT);

    // ---- node encoder (fused f32->bf16, col-blocked h out) ----
    gemm_v2<0><<<GEMM_BLOCKS, 256, 0, stream>>>(x, WT, bnode, h, nullptr,
                                                nullptr, nullptr, nullptr);

    // ---- GIN layers ----
    for (int i = 0; i < N_LAYERS; ++i) {
        float* bn_sum = bn_stats + (size_t)i * 2 * DIM;
        float* bn_sumsq = bn_sum + DIM;
        aggregate_cb<<<AGG_BLOCKS, 256, 0, stream>>>(h, row_ptr, col_src, agg);
        gemm_v2<1><<<GEMM_BLOCKS, 256, 0, stream>>>(
            agg, WT + (size_t)(1 + i) * DIM * DIM, b1 + i * DIM, y, bn_sum,
            bn_sumsq, nullptr, nullptr);
        gemm_v2<2><<<GEMM_BLOCKS, 256, 0, stream>>>(
            y, WT + (size_t)(4 + i) * DIM * DIM, b2 + i * DIM, h, bn_sum,
            bn_sumsq, gamma + i * DIM, beta + i * DIM);
    }

    // ---- global add pool ----
    pool_cb<<<POOL_BLOCKS, 256, 0, stream>>>(h, batch, out);
}

// Round 10
// 611.181 us; speedup vs baseline: 2.1320x; 1.6617x over previous
//
#include <hip/hip_runtime.h>

#define N_NODES 100000
#define M_PAD   100096   // multiple of 128 rows
#define N_EDGES 3200000
#define DIM 128
#define N_LAYERS 3
#define NUM_GRAPHS 128
#define BN_EPS 1e-5f

// ---- binned CSR build parameters ----
#define DST_SHIFT 7
#define BUCKET_NODES 128
#define N_BUCKETS ((N_NODES + BUCKET_NODES - 1) / BUCKET_NODES)  // 782
#define BUCKET_CAP 4864
#define EDGES_PER_BLOCK 16384
#define BIN_BLOCKS ((N_EDGES + EDGES_PER_BLOCK - 1) / EDGES_PER_BLOCK)  // 196
#define N_BANDS 64   // used: (src>>11) in [0,49)

#define AGG_BLOCKS 25000          // 4 nodes per block; 25000 % 8 == 0
#define AGG_CHUNK  (AGG_BLOCKS / 8)   // 3125 blocks per XCD

typedef unsigned int uint32;
typedef unsigned short u16;
typedef __attribute__((ext_vector_type(8))) short bf16x8;
typedef __attribute__((ext_vector_type(4))) float f32x4;

__device__ __forceinline__ float bf2f(u16 u) {
    union { uint32 i; float f; } c;
    c.i = ((uint32)u) << 16;
    return c.f;
}
__device__ __forceinline__ u16 f2bf(float f) {
    union { float f; uint32 i; } c;
    c.f = f;
    uint32 i = c.i;
    return (u16)((i + 0x7FFFu + ((i >> 16) & 1u)) >> 16);
}
__device__ __forceinline__ float lo_bf(uint32 v) {
    union { uint32 i; float f; } c;
    c.i = v << 16;
    return c.f;
}
__device__ __forceinline__ float hi_bf(uint32 v) {
    union { uint32 i; float f; } c;
    c.i = v & 0xFFFF0000u;
    return c.f;
}
__device__ __forceinline__ uint32 pack_bf2(float a, float b) {
    return ((uint32)f2bf(b) << 16) | (uint32)f2bf(a);
}
__device__ __forceinline__ void unpack_add8(float* acc, uint4 v) {
    acc[0] += lo_bf(v.x); acc[1] += hi_bf(v.x);
    acc[2] += lo_bf(v.y); acc[3] += hi_bf(v.y);
    acc[4] += lo_bf(v.z); acc[5] += hi_bf(v.z);
    acc[6] += lo_bf(v.w); acc[7] += hi_bf(v.w);
}

// ---------------------------------------------------------------------------
// zero_misc: one launch replaces all memsets
// ---------------------------------------------------------------------------
__global__ __launch_bounds__(256) void zero_misc(int* __restrict__ gcur,
                                                 float* __restrict__ bn_stats,
                                                 float* __restrict__ outp,
                                                 uint32* __restrict__ aggpad32) {
    int i = blockIdx.x * 256 + threadIdx.x;
    if (i < N_BUCKETS) gcur[i] = 0;
    if (i < N_LAYERS * 2 * DIM) bn_stats[i] = 0.f;
    if (i < NUM_GRAPHS * DIM) outp[i] = 0.f;
    if (i < (M_PAD - N_NODES) * DIM / 2) aggpad32[i] = 0;
}

// ---------------------------------------------------------------------------
// Stage A: bin edges by dst bucket (2-pass, coalesced). packed = src|(dst&127)<<17
// ---------------------------------------------------------------------------
__global__ __launch_bounds__(256) void bin_by_dst(const int* __restrict__ src,
                                                  const int* __restrict__ dst,
                                                  int* __restrict__ gcur,
                                                  uint32* __restrict__ packed) {
    __shared__ int cnt[N_BUCKETS];
    __shared__ int cur[N_BUCKETS];
    int t = threadIdx.x;
    int e0 = blockIdx.x * EDGES_PER_BLOCK;
    for (int i = t; i < N_BUCKETS; i += 256) cnt[i] = 0;
    __syncthreads();

    for (int j = 0; j < EDGES_PER_BLOCK / 256; ++j) {
        int e = e0 + j * 256 + t;
        if (e < N_EDGES) atomicAdd(&cnt[dst[e] >> DST_SHIFT], 1);
    }
    __syncthreads();
    for (int i = t; i < N_BUCKETS; i += 256) {
        int c = cnt[i];
        cur[i] = c ? atomicAdd(&gcur[i], c) : 0;
    }
    __syncthreads();
    for (int j = 0; j < EDGES_PER_BLOCK / 256; ++j) {
        int e = e0 + j * 256 + t;
        if (e < N_EDGES) {
            int d = dst[e];
            int b = d >> DST_SHIFT;
            int pos = atomicAdd(&cur[b], 1);
            if (pos < BUCKET_CAP)
                packed[(size_t)b * BUCKET_CAP + pos] =
                    (uint32)src[e] | ((uint32)(d & (BUCKET_NODES - 1)) << 17);
        }
    }
}

// ---------------------------------------------------------------------------
__global__ void scan_buckets(const int* __restrict__ gcur, int* __restrict__ obase,
                             int* __restrict__ row_ptr) {
    __shared__ int s[N_BUCKETS];
    int t = threadIdx.x;
    for (int i = t; i < N_BUCKETS; i += 256) {
        int c = gcur[i];
        s[i] = (c > BUCKET_CAP) ? BUCKET_CAP : c;
    }
    __syncthreads();
    if (t == 0) {
        int run = 0;
        for (int i = 0; i < N_BUCKETS; ++i) {
            int c = s[i];
            s[i] = run;
            run += c;
        }
        row_ptr[N_NODES] = run;
    }
    __syncthreads();
    for (int i = t; i < N_BUCKETS; i += 256) obase[i] = s[i];
}

// ---------------------------------------------------------------------------
// Stage B: per bucket — row_ptr, band-sort by src>>11 (restored: the XCD
// phase-sweep locality in aggregate depends on it), place into col_src.
// ---------------------------------------------------------------------------
__global__ __launch_bounds__(256) void build_buckets(const uint32* __restrict__ packed,
                                                     const int* __restrict__ gcur,
                                                     const int* __restrict__ obase_arr,
                                                     int* __restrict__ row_ptr,
                                                     int* __restrict__ col_src) {
    __shared__ uint32 ed[BUCKET_CAP];
    __shared__ uint32 ed2[BUCKET_CAP];
    __shared__ int bandcur[N_BANDS];
    __shared__ int ncnt[BUCKET_NODES];
    __shared__ int ncur[BUCKET_NODES];
    int b = blockIdx.x, t = threadIdx.x;
    int cnt = gcur[b];
    if (cnt > BUCKET_CAP) cnt = BUCKET_CAP;
    int obase = obase_arr[b];
    int n0 = b * BUCKET_NODES;

    if (t < N_BANDS) bandcur[t] = 0;
    if (t < BUCKET_NODES) ncnt[t] = 0;
    __syncthreads();

    const uint32* reg = packed + (size_t)b * BUCKET_CAP;
    for (int i = t; i < cnt; i += 256) {
        uint32 v = reg[i];
        ed[i] = v;
        atomicAdd(&bandcur[(v & 0x1FFFFu) >> 11], 1);
        atomicAdd(&ncnt[v >> 17], 1);
    }
    __syncthreads();

    if (t == 0) {
        int run = 0;
        for (int w = 0; w < N_BANDS; ++w) {
            int c = bandcur[w];
            bandcur[w] = run;
            run += c;
        }
    }
    int myc = (t < BUCKET_NODES) ? ncnt[t] : 0;
    if (t < BUCKET_NODES) ncur[t] = myc;
    __syncthreads();
    for (int off = 1; off < BUCKET_NODES; off <<= 1) {
        int v = 0;
        if (t < BUCKET_NODES && t >= off) v = ncur[t - off];
        __syncthreads();
        if (t < BUCKET_NODES) ncur[t] += v;
        __syncthreads();
    }
    if (t < BUCKET_NODES) {
        int excl = ncur[t] - myc;
        ncur[t] = excl;
        int gn = n0 + t;
        if (gn < N_NODES) row_ptr[gn] = obase + excl;
    }
    __syncthreads();

    // counting sort by src band
    for (int i = t; i < cnt; i += 256) {
        uint32 v = ed[i];
        int p = atomicAdd(&bandcur[(v & 0x1FFFFu) >> 11], 1);
        ed2[p] = v;
    }
    __syncthreads();

    // place into per-node slots (band order preserved up to scheduling noise)
    for (int i = t; i < cnt; i += 256) {
        uint32 v = ed2[i];
        int slot = atomicAdd(&ncur[v >> 17], 1);
        col_src[obase + slot] = (int)(v & 0x1FFFFu);
    }
}

// ---------------------------------------------------------------------------
// All 7 weight matrices -> WT bf16, transposed (n-major) AND pre-swizzled:
// element (n,k) at byte (n*256 + k*2) ^ ((n&7)<<4) within its matrix.
// ---------------------------------------------------------------------------
__global__ void cvt_wt_all(const float* __restrict__ Wn, const float* __restrict__ W1,
                           const float* __restrict__ W2, u16* __restrict__ WT) {
    int m = blockIdx.x >> 7, n = blockIdx.x & 127, k = threadIdx.x;
    const float* src = (m == 0) ? Wn
                     : (m <= 3) ? W1 + (size_t)(m - 1) * DIM * DIM
                                : W2 + (size_t)(m - 4) * DIM * DIM;
    int L = n * 256 + k * 2;
    int Ls = L ^ ((n & 7) << 4);
    *(u16*)((char*)WT + (size_t)m * 32768 + Ls) = f2bf(src[(size_t)k * DIM + n]);
}

// ---------------------------------------------------------------------------
// Aggregation (row-major, quad-per-edge, XCD-chunked): one wave per node;
// quad q loads one full 256 B row per edge via dwordx4 (16 B/lane), 4 edges
// in flight per quad; f32 accum; cross-quad shfl reduce.
// Block swizzle: XCD x = bid%8 gets the CONTIGUOUS chunk [x*3125, (x+1)*3125)
// of blocks -> each XCD owns 12500 consecutive nodes whose band-sorted lists
// are swept in phase -> src window per XCD stays L2-resident.
// ---------------------------------------------------------------------------
__global__ __launch_bounds__(256) void aggregate_bf(const u16* __restrict__ h,
                                                    const int* __restrict__ row_ptr,
                                                    const int* __restrict__ col_src,
                                                    u16* __restrict__ agg) {
    int wg = (blockIdx.x & 7) * AGG_CHUNK + (blockIdx.x >> 3);  // bijective
    int wv = wg * 4 + (threadIdx.x >> 6);
    int lane = threadIdx.x & 63;
    int q = lane >> 4, c = lane & 15;
    if (wv >= N_NODES) return;
    int beg = row_ptr[wv], end = row_ptr[wv + 1];
    const uint4* h4 = (const uint4*)h;   // one row = 16 uint4

    float acc[8];
#pragma unroll
    for (int j = 0; j < 8; ++j) acc[j] = 0.f;

    if (q == 0) {  // self contribution (1+eps)*h, eps=0
        uint4 v = h4[(size_t)wv * 16 + c];
        unpack_add8(acc, v);
    }
    int e = beg + q;
    for (; e + 12 < end; e += 16) {
        int i0 = col_src[e];
        int i1 = col_src[e + 4];
        int i2 = col_src[e + 8];
        int i3 = col_src[e + 12];
        uint4 v0 = h4[(size_t)i0 * 16 + c];
        uint4 v1 = h4[(size_t)i1 * 16 + c];
        uint4 v2 = h4[(size_t)i2 * 16 + c];
        uint4 v3 = h4[(size_t)i3 * 16 + c];
        unpack_add8(acc, v0);
        unpack_add8(acc, v1);
        unpack_add8(acc, v2);
        unpack_add8(acc, v3);
    }
    for (; e < end; e += 4) {
        uint4 v0 = h4[(size_t)col_src[e] * 16 + c];
        unpack_add8(acc, v0);
    }
#pragma unroll
    for (int j = 0; j < 8; ++j) {
        acc[j] += __shfl_xor(acc[j], 16);
        acc[j] += __shfl_xor(acc[j], 32);
    }
    if (q == 0) {
        uint4 o;
        o.x = pack_bf2(acc[0], acc[1]);
        o.y = pack_bf2(acc[2], acc[3]);
        o.z = pack_bf2(acc[4], acc[5]);
        o.w = pack_bf2(acc[6], acc[7]);
        *(uint4*)&agg[(size_t)wv * DIM + c * 8] = o;
    }
}

// ---------------------------------------------------------------------------
// GEMM v2.1: 128 rows x 128 cols per block (256 thr = 4 waves).
// B (32 KB, pre-swizzled) in LDS; A loads hoisted before the stage barrier.
// MODE 0: A = f32 x (fused cvt)              -> h = A@W + b
// MODE 1: A = bf16 agg, BN stats epilogue    -> y = A@W1 + b1
// MODE 2: A = bf16 y, BN+ReLU pre, ReLU post -> h = relu(relu(BN(y))@W2 + b2)
// All outputs row-major.
// ---------------------------------------------------------------------------
template <int MODE>
__global__ __launch_bounds__(256) void gemm_v2(const void* __restrict__ Av,
                                               const u16* __restrict__ WTs,
                                               const float* __restrict__ bias,
                                               u16* __restrict__ outp,
                                               float* __restrict__ bn_sum,
                                               float* __restrict__ bn_sumsq,
                                               const float* __restrict__ gamma,
                                               const float* __restrict__ beta) {
    __shared__ u16 sB[DIM * DIM];     // 32 KB swizzled
    __shared__ float sc_[DIM];
    __shared__ float sh_[DIM];
    __shared__ float ls[4][DIM];
    __shared__ float lq[4][DIM];

    int t = threadIdx.x;
    int wid = t >> 6, lane = t & 63;
    int hw = lane >> 4, c = lane & 15;
    int row0 = blockIdx.x * 128 + wid * 32;

    // ---- issue A loads FIRST ----
    bf16x8 a[2][4];
    float4 af[2][4][2];
#pragma unroll
    for (int rf = 0; rf < 2; ++rf) {
        int row = row0 + rf * 16 + c;
#pragma unroll
        for (int ks = 0; ks < 4; ++ks) {
            int k0 = ks * 32 + hw * 8;
            if (MODE == 0) {
                const float* xf = (const float*)Av;
                af[rf][ks][0] = make_float4(0.f, 0.f, 0.f, 0.f);
                af[rf][ks][1] = af[rf][ks][0];
                if (row < N_NODES) {
                    af[rf][ks][0] = *(const float4*)&xf[(size_t)row * DIM + k0];
                    af[rf][ks][1] = *(const float4*)&xf[(size_t)row * DIM + k0 + 4];
                }
            } else {
                const u16* Ab = (const u16*)Av;
                a[rf][ks] = *(const bf16x8*)&Ab[(size_t)row * DIM + k0];
            }
        }
    }

    // ---- stage B (linear copy; swizzle baked into global layout) ----
    {
        const uint4* Wg = (const uint4*)WTs;
        uint4* sB4 = (uint4*)sB;
#pragma unroll
        for (int i = 0; i < 8; ++i) sB4[i * 256 + t] = Wg[i * 256 + t];
    }
    if (MODE == 2 && t < DIM) {
        const float invN = 1.0f / (float)N_NODES;
        float mean = bn_sum[t] * invN;
        float var = fmaxf(bn_sumsq[t] * invN - mean * mean, 0.f);
        float rs = rsqrtf(var + BN_EPS);
        float sc = gamma[t] * rs;
        sc_[t] = sc;
        sh_[t] = beta[t] - mean * sc;
    }
    __syncthreads();

    // ---- finish A fragments in registers ----
#pragma unroll
    for (int rf = 0; rf < 2; ++rf) {
#pragma unroll
        for (int ks = 0; ks < 4; ++ks) {
            int k0 = ks * 32 + hw * 8;
            if (MODE == 0) {
                union { bf16x8 v; u16 u[8]; } ua;
                float4 v0 = af[rf][ks][0], v1 = af[rf][ks][1];
                ua.u[0] = f2bf(v0.x); ua.u[1] = f2bf(v0.y);
                ua.u[2] = f2bf(v0.z); ua.u[3] = f2bf(v0.w);
                ua.u[4] = f2bf(v1.x); ua.u[5] = f2bf(v1.y);
                ua.u[6] = f2bf(v1.z); ua.u[7] = f2bf(v1.w);
                a[rf][ks] = ua.v;
            } else if (MODE == 2) {
                union { bf16x8 v; u16 u[8]; } ua;
                ua.v = a[rf][ks];
#pragma unroll
                for (int j = 0; j < 8; ++j) {
                    float f = bf2f(ua.u[j]);
                    f = fmaxf(fmaf(f, sc_[k0 + j], sh_[k0 + j]), 0.f);
                    ua.u[j] = f2bf(f);
                }
                a[rf][ks] = ua.v;
            }
        }
    }

    // ---- MFMA from LDS B ----
    f32x4 acc[2][8];
#pragma unroll
    for (int rf = 0; rf < 2; ++rf)
#pragma unroll
        for (int nf = 0; nf < 8; ++nf) acc[rf][nf] = (f32x4){0.f, 0.f, 0.f, 0.f};

    int swz = (c & 7) << 4;
#pragma unroll
    for (int ks = 0; ks < 4; ++ks) {
#pragma unroll
        for (int nf = 0; nf < 8; ++nf) {
            int L = (nf * 4096 + c * 256 + ks * 64 + hw * 16) ^ swz;
            bf16x8 b = *(const bf16x8*)((const char*)sB + L);
            acc[0][nf] = __builtin_amdgcn_mfma_f32_16x16x32_bf16(a[0][ks], b, acc[0][nf], 0, 0, 0);
            acc[1][nf] = __builtin_amdgcn_mfma_f32_16x16x32_bf16(a[1][ks], b, acc[1][nf], 0, 0, 0);
        }
    }

    // ---- epilogue ----
    float s_[8], q_[8];
#pragma unroll
    for (int nf = 0; nf < 8; ++nf) { s_[nf] = 0.f; q_[nf] = 0.f; }

#pragma unroll
    for (int rf = 0; rf < 2; ++rf) {
        int rbase = row0 + rf * 16 + hw * 4;
#pragma unroll
        for (int nf = 0; nf < 8; ++nf) {
            float bv = bias[nf * 16 + c];
#pragma unroll
            for (int r = 0; r < 4; ++r) {
                float v = acc[rf][nf][r] + bv;
                if (MODE == 2) v = fmaxf(v, 0.f);
                outp[(size_t)(rbase + r) * DIM + nf * 16 + c] = f2bf(v);
                if (MODE == 1) {
                    float m = (rbase + r < N_NODES) ? v : 0.f;
                    s_[nf] += m;
                    q_[nf] += m * m;
                }
            }
        }
    }

    if (MODE == 1) {
#pragma unroll
        for (int nf = 0; nf < 8; ++nf) {
            s_[nf] += __shfl_xor(s_[nf], 16);
            s_[nf] += __shfl_xor(s_[nf], 32);
            q_[nf] += __shfl_xor(q_[nf], 16);
            q_[nf] += __shfl_xor(q_[nf], 32);
        }
        if (lane < 16) {
#pragma unroll
            for (int nf = 0; nf < 8; ++nf) {
                ls[wid][nf * 16 + c] = s_[nf];
                lq[wid][nf * 16 + c] = q_[nf];
            }
        }
        __syncthreads();
        if (t < DIM) {
            atomicAdd(&bn_sum[t], ls[0][t] + ls[1][t] + ls[2][t] + ls[3][t]);
            atomicAdd(&bn_sumsq[t], lq[0][t] + lq[1][t] + lq[2][t] + lq[3][t]);
        }
    }
}

// ---------------------------------------------------------------------------
// Global add pool (row-major bf16 h, f32 out); batch sorted
// ---------------------------------------------------------------------------
__global__ __launch_bounds__(256) void pool_bf(const u16* __restrict__ h,
                                               const int* __restrict__ batch,
                                               float* __restrict__ out) {
    int wv = (blockIdx.x * 256 + threadIdx.x) >> 6;
    int lane = threadIdx.x & 63;
    int base = wv * 32;
    if (base >= N_NODES) return;
    int end = base + 32;
    if (end > N_NODES) end = N_NODES;
    const uint32* h32 = (const uint32*)h;
    float ax = 0.f, ay = 0.f;
    int curg = batch[base];
    for (int n = base; n < end; ++n) {
        int g = batch[n];
        if (g != curg) {
            atomicAdd(&out[curg * DIM + lane * 2], ax);
            atomicAdd(&out[curg * DIM + lane * 2 + 1], ay);
            ax = 0.f;
            ay = 0.f;
            curg = g;
        }
        uint32 v = h32[(size_t)n * 64 + lane];
        ax += lo_bf(v);
        ay += hi_bf(v);
    }
    atomicAdd(&out[curg * DIM + lane * 2], ax);
    atomicAdd(&out[curg * DIM + lane * 2 + 1], ay);
}

// ---------------------------------------------------------------------------
extern "C" void kernel_launch(void* const* d_in, const int* in_sizes, int n_in,
                              void* d_out, int out_size, void* d_ws, size_t ws_size,
                              hipStream_t stream) {
    const float* x     = (const float*)d_in[0];
    const int*   ei    = (const int*)d_in[1];
    const int*   batch = (const int*)d_in[2];
    const float* Wn    = (const float*)d_in[3];
    const float* bnode = (const float*)d_in[4];
    const float* W1    = (const float*)d_in[5];
    const float* b1    = (const float*)d_in[6];
    const float* gamma = (const float*)d_in[7];
    const float* beta  = (const float*)d_in[8];
    const float* W2    = (const float*)d_in[9];
    const float* b2    = (const float*)d_in[10];
    float* out = (float*)d_out;

    const int* e_src = ei;
    const int* e_dst = ei + N_EDGES;

    // workspace layout
    const size_t MD = (size_t)M_PAD * DIM;
    u16* h   = (u16*)d_ws;                  // row-major
    u16* agg = h + MD;                      // row-major
    u16* y   = agg + MD;                    // row-major
    u16* WT  = y + MD;                      // 7 * 128 * 128 bf16, pre-swizzled
    int* row_ptr = (int*)(WT + 7 * DIM * DIM);
    int* col_src = row_ptr + N_NODES + 1;
    int* gcur    = col_src + N_EDGES;
    int* obase   = gcur + N_BUCKETS;
    float* bn_stats = (float*)(obase + N_BUCKETS);   // 3 layers * 2 * DIM
    // packed aliases y: used only during CSR build, before any GEMM writes y
    uint32* packed = (uint32*)y;            // 782*4864*4 B = 15.2 MB <= 25.6 MB

    const int GEMM_BLOCKS = M_PAD / 128;                     // 782
    const int POOL_BLOCKS = (((N_NODES + 31) / 32) * 64 + 255) / 256;

    // ---- init + CSR build ----
    zero_misc<<<64, 256, 0, stream>>>(gcur, bn_stats, out,
                                      (uint32*)(agg + (size_t)N_NODES * DIM));
    bin_by_dst<<<BIN_BLOCKS, 256, 0, stream>>>(e_src, e_dst, gcur, packed);
    scan_buckets<<<1, 256, 0, stream>>>(gcur, obase, row_ptr);
    build_buckets<<<N_BUCKETS, 256, 0, stream>>>(packed, gcur, obase, row_ptr, col_src);

    // ---- weights (transposed + swizzled bf16) ----
    cvt_wt_all<<<7 * DIM, DIM, 0, stream>>>(Wn, W1, W2, WT);

    // ---- node encoder (fused f32->bf16) ----
    gemm_v2<0><<<GEMM_BLOCKS, 256, 0, stream>>>(x, WT, bnode, h, nullptr,
                                                nullptr, nullptr, nullptr);

    // ---- GIN layers ----
    for (int i = 0; i < N_LAYERS; ++i) {
        float* bn_sum = bn_stats + (size_t)i * 2 * DIM;
        float* bn_sumsq = bn_sum + DIM;
        aggregate_bf<<<AGG_BLOCKS, 256, 0, stream>>>(h, row_ptr, col_src, agg);
        gemm_v2<1><<<GEMM_BLOCKS, 256, 0, stream>>>(
            agg, WT + (size_t)(1 + i) * DIM * DIM, b1 + i * DIM, y, bn_sum,
            bn_sumsq, nullptr, nullptr);
        gemm_v2<2><<<GEMM_BLOCKS, 256, 0, stream>>>(
            y, WT + (size_t)(4 + i) * DIM * DIM, b2 + i * DIM, h, bn_sum,
            bn_sumsq, gamma + i * DIM, beta + i * DIM);
    }

    // ---- global add pool ----
    pool_bf<<<POOL_BLOCKS, 256, 0, stream>>>(h, batch, out);
}